// Round 3
// baseline (442.755 us; speedup 1.0000x reference)
//
#include <hip/hip_runtime.h>
#include <hip/hip_cooperative_groups.h>
#include <math.h>

namespace cg = cooperative_groups;

#define B_ 64
#define E_ 512
#define N_ 2048
#define EPSF 1e-8f

// ws layout (float slots)
#define OFF_ROWMEAN 0              // B*E = 32768
#define OFF_ROWINV  32768          // B*E = 32768
#define OFF_COLPART 65536          // 16*B*N = 2097152
#define OFF_MM      2162688        // 8 u32 (min[3], max[3])
#define OFF_YG      2162696        // B*64*2048 = 8388608 (pre-swizzled LDS image)
#define OFF_ZPART   10551304       // 16*B*4096 = 4194304
// total ~14.7M floats ~59 MB

// order-preserving float<->uint map for atomic min/max
__device__ __forceinline__ unsigned mapf(float x) {
    unsigned u = __float_as_uint(x);
    return (u & 0x80000000u) ? ~u : (u | 0x80000000u);
}
__device__ __forceinline__ float unmapf(unsigned m) {
    unsigned u = (m & 0x80000000u) ? (m ^ 0x80000000u) : ~m;
    return __uint_as_float(u);
}

// ---------- kernel 1: fused row stats + col partials + Y production ----------
// grid (16, B), block 256 = 4 waves; wave w rows [ec*32+8w, +8).
// Wave's rows contain exactly one Y pair (r%8==3,4) -> Y row o = ec*4+w.
// Y stored PRE-SWIZZLED per 128-K chunk: word(o, 4m+j) = o*128 + 4*(m^(o>>3)) + j
__global__ __launch_bounds__(256) void k_stats(const float* __restrict__ x,
                                               float* __restrict__ rowmean,
                                               float* __restrict__ rowinv,
                                               float* __restrict__ colpart,
                                               float* __restrict__ Yg,
                                               unsigned* __restrict__ mm) {
    __shared__ __align__(16) float cs[4][N_];   // 32 KB
    int b = blockIdx.y, ec = blockIdx.x;
    int t = threadIdx.x, w = t >> 6, lane = t & 63;
    if (ec == 0 && b == 0 && t < 6) mm[t] = (t < 3) ? 0xFFFFFFFFu : 0u;

    float colacc[32];
#pragma unroll
    for (int i = 0; i < 32; ++i) colacc[i] = 0.f;
    int ebase = ec * 32 + w * 8;
    int o = ebase >> 3;                 // Y row this wave produces
    float4 y3[8], y4[8];
    float m0 = 0.f, s0 = 0.f, m1 = 0.f, s1 = 0.f;

#pragma unroll
    for (int r = 0; r < 8; ++r) {
        int e = ebase + r;
        const float4* row = (const float4*)(x + ((size_t)b * E_ + e) * N_);
        float s = 0.f, sq = 0.f;
#pragma unroll
        for (int i = 0; i < 8; ++i) {
            float4 v = row[lane + 64 * i];
            if (r == 3) y3[i] = v;
            if (r == 4) y4[i] = v;
            s += v.x + v.y + v.z + v.w;
            sq = fmaf(v.x, v.x, sq);
            sq = fmaf(v.y, v.y, sq);
            sq = fmaf(v.z, v.z, sq);
            sq = fmaf(v.w, v.w, sq);
            colacc[4 * i + 0] += v.x;
            colacc[4 * i + 1] += v.y;
            colacc[4 * i + 2] += v.z;
            colacc[4 * i + 3] += v.w;
        }
#pragma unroll
        for (int m = 32; m; m >>= 1) {   // butterfly: ALL lanes get totals
            s += __shfl_xor(s, m, 64);
            sq += __shfl_xor(sq, m, 64);
        }
        float mean = s * (1.0f / N_);
        float var = sq - s * s * (1.0f / N_);
        if (var < 0.f) var = 0.f;
        float inv = 1.0f / (sqrtf(var) + EPSF);
        if (lane == 0) {
            rowmean[b * E_ + e] = mean;
            rowinv[b * E_ + e] = inv;
        }
        if (r == 3) { m0 = mean; s0 = inv; }
        if (r == 4) { m1 = mean; s1 = inv; }
    }

    // emit Y row o (pre-swizzled; 2x 512B permuted segments per store)
    int swc = o >> 3;
#pragma unroll
    for (int i = 0; i < 8; ++i) {
        int ki = lane + 64 * i;          // float4 index in row, 0..511
        int kc = ki >> 5;                // 128-float K chunk
        int mi = ki & 31;
        float4 a = y3[i], c = y4[i], yv;
        yv.x = 0.5f * ((a.x - m0) * s0 + (c.x - m1) * s1);
        yv.y = 0.5f * ((a.y - m0) * s0 + (c.y - m1) * s1);
        yv.z = 0.5f * ((a.z - m0) * s0 + (c.z - m1) * s1);
        yv.w = 0.5f * ((a.w - m0) * s0 + (c.w - m1) * s1);
        *(float4*)&Yg[(((size_t)b * 16 + kc) * 64 + o) * 128 + 4 * (mi ^ swc)] = yv;
    }

    // col partials
    float4* slice = (float4*)cs[w];
#pragma unroll
    for (int i = 0; i < 8; ++i)
        slice[lane + 64 * i] = make_float4(colacc[4 * i], colacc[4 * i + 1],
                                           colacc[4 * i + 2], colacc[4 * i + 3]);
    __syncthreads();
    float* cp = colpart + ((size_t)ec * B_ + b) * N_;
    for (int c = t; c < N_; c += 256)
        cp[c] = cs[0][c] + cs[1][c] + cs[2][c] + cs[3][c];
}

// ---------- kernel 2: Z = Y Y^T partials; one wave per (b, kchunk) ----------
// Stages the pre-swizzled 32KB chunk with 32 coalesced float4 loads,
// then 8x8 register-tile syrk with conflict-free ds_read_b128.
__global__ __launch_bounds__(64) void k_z2(const float* __restrict__ Yg,
                                           float* __restrict__ zpart) {
    __shared__ __align__(16) float Y[64 * 128];   // 32 KB
    int b = blockIdx.x, kc = blockIdx.y;
    int lane = threadIdx.x;
    const float4* src = (const float4*)(Yg + ((size_t)b * 16 + kc) * 8192);
    float4* dst = (float4*)Y;
#pragma unroll
    for (int it = 0; it < 32; ++it) dst[lane + 64 * it] = src[lane + 64 * it];
    __syncthreads();

    int ti = lane >> 3, tj = lane & 7;
    float acc[8][8];
#pragma unroll
    for (int i = 0; i < 8; ++i)
#pragma unroll
        for (int j = 0; j < 8; ++j) acc[i][j] = 0.f;

#pragma unroll 2
    for (int m4 = 0; m4 < 32; ++m4) {
        float4 av[8], bv[8];
#pragma unroll
        for (int a = 0; a < 8; ++a)
            av[a] = *(const float4*)&Y[(8 * ti + a) * 128 + 4 * (m4 ^ ti)];
#pragma unroll
        for (int c = 0; c < 8; ++c)
            bv[c] = *(const float4*)&Y[(8 * tj + c) * 128 + 4 * (m4 ^ tj)];
#pragma unroll
        for (int a = 0; a < 8; ++a)
#pragma unroll
            for (int c = 0; c < 8; ++c) {
                acc[a][c] = fmaf(av[a].x, bv[c].x, acc[a][c]);
                acc[a][c] = fmaf(av[a].y, bv[c].y, acc[a][c]);
                acc[a][c] = fmaf(av[a].z, bv[c].z, acc[a][c]);
                acc[a][c] = fmaf(av[a].w, bv[c].w, acc[a][c]);
            }
    }
    float* zp = zpart + ((size_t)kc * B_ + b) * 4096;
#pragma unroll
    for (int a = 0; a < 8; ++a) {
        int rr = (8 * ti + a) * 64 + 8 * tj;
        *(float4*)&zp[rr]     = make_float4(acc[a][0], acc[a][1], acc[a][2], acc[a][3]);
        *(float4*)&zp[rr + 4] = make_float4(acc[a][4], acc[a][5], acc[a][6], acc[a][7]);
    }
}

// ---------- kernel 3 (cooperative): views + global min/max + normalize ----------
// grid (B, 3), block 256; pixels live in registers across grid.sync()
__global__ __launch_bounds__(256) void k_viewsnorm(const float* __restrict__ rowmean,
                                                   const float* __restrict__ colpart,
                                                   const float* __restrict__ zpart,
                                                   unsigned* __restrict__ mm,
                                                   float* __restrict__ out) {
    cg::grid_group grid = cg::this_grid();
    int b = blockIdx.x, v = blockIdx.y;
    int t = threadIdx.x;
    __shared__ float g[2116];
    __shared__ int   ti0[64];
    __shared__ int   ti1[64];
    __shared__ float tw[64];
    __shared__ float smin[4], smax[4];
    __shared__ float slo, sinv;
    __shared__ int   szero;

    int gs = (v == 0) ? 23 : 46;
    if (v < 2) {
        int L = (v == 0) ? 512 : 2048;
        int gg = gs * gs;
        for (int i = t; i < gg; i += 256) {
            float val = 0.f;
            if (i < L) {
                if (v == 0) {
                    val = rowmean[b * E_ + i];
                } else {
#pragma unroll
                    for (int ch = 0; ch < 16; ++ch)
                        val += colpart[((size_t)ch * B_ + b) * N_ + i];
                    val *= (1.0f / 512.0f);
                }
            }
            g[i] = val;
        }
        if (t < 64) {
            double scd = (double)gs / 64.0;
            double sp = ((double)t + 0.5) * scd - 0.5;
            if (sp < 0.0) sp = 0.0;
            double up = (double)(gs - 1);
            if (sp > up) sp = up;
            int i0 = (int)sp;
            ti0[t] = i0;
            ti1[t] = (i0 + 1 < gs) ? i0 + 1 : gs - 1;
            tw[t] = (float)(sp - (double)i0);
        }
    }
    __syncthreads();

    float vals[16];
    float lmin = INFINITY, lmax = -INFINITY;
#pragma unroll 1
    for (int it = 0; it < 16; ++it) {
        int pix = t + 256 * it;
        float val;
        if (v == 2) {
            val = 0.f;
#pragma unroll
            for (int s = 0; s < 16; ++s)
                val += zpart[((size_t)s * B_ + b) * 4096 + pix];
        } else {
            int o = pix >> 6, p = pix & 63;
            int i0 = ti0[o], i1 = ti1[o];
            float wh = tw[o];
            int j0 = ti0[p], j1 = ti1[p];
            float ww = tw[p];
            float top = g[i0 * gs + j0] * (1.f - ww) + g[i0 * gs + j1] * ww;
            float bot = g[i1 * gs + j0] * (1.f - ww) + g[i1 * gs + j1] * ww;
            val = top * (1.f - wh) + bot * wh;
        }
        vals[it] = val;
        lmin = fminf(lmin, val);
        lmax = fmaxf(lmax, val);
    }

    int lane = t & 63, wid = t >> 6;
#pragma unroll
    for (int m = 32; m; m >>= 1) {
        lmin = fminf(lmin, __shfl_xor(lmin, m, 64));
        lmax = fmaxf(lmax, __shfl_xor(lmax, m, 64));
    }
    if (lane == 0) { smin[wid] = lmin; smax[wid] = lmax; }
    __syncthreads();
    if (t == 0) {
        float mn = fminf(fminf(smin[0], smin[1]), fminf(smin[2], smin[3]));
        float mx = fmaxf(fmaxf(smax[0], smax[1]), fmaxf(smax[2], smax[3]));
        atomicMin(&mm[v], mapf(mn));
        atomicMax(&mm[3 + v], mapf(mx));
        __threadfence();
    }

    grid.sync();

    if (t == 0) {   // coherent read via atomic RMW
        float lo = unmapf(atomicAdd(&mm[v], 0u));
        float hi = unmapf(atomicAdd(&mm[3 + v], 0u));
        float d = hi - lo;
        szero = (d < EPSF);
        slo = lo;
        sinv = 1.0f / (d + EPSF);
    }
    __syncthreads();
    float lo = slo, inv = sinv;
    int zero = szero;
    size_t base = ((size_t)b * 3 + v) * 4096;
#pragma unroll 1
    for (int it = 0; it < 16; ++it) {
        int pix = t + 256 * it;
        out[base + pix] = zero ? 0.f : (vals[it] - lo) * inv;
    }
}

extern "C" void kernel_launch(void* const* d_in, const int* in_sizes, int n_in,
                              void* d_out, int out_size, void* d_ws, size_t ws_size,
                              hipStream_t stream) {
    const float* x = (const float*)d_in[0];
    float* ws = (float*)d_ws;
    float* rowmean = ws + OFF_ROWMEAN;
    float* rowinv  = ws + OFF_ROWINV;
    float* colpart = ws + OFF_COLPART;
    unsigned* mm   = (unsigned*)(ws + OFF_MM);
    float* Yg      = ws + OFF_YG;
    float* zpart   = ws + OFF_ZPART;
    float* out     = (float*)d_out;

    k_stats<<<dim3(16, B_), 256, 0, stream>>>(x, rowmean, rowinv, colpart, Yg, mm);
    k_z2<<<dim3(B_, 16), 64, 0, stream>>>(Yg, zpart);

    const float* rm = rowmean;
    const float* cp = colpart;
    const float* zp = zpart;
    void* args[] = {(void*)&rm, (void*)&cp, (void*)&zp, (void*)&mm, (void*)&out};
    hipLaunchCooperativeKernel((const void*)k_viewsnorm, dim3(B_, 3), dim3(256),
                               args, 0, stream);
}

// Round 4
// 425.987 us; speedup vs baseline: 1.0394x; 1.0394x over previous
//
#include <hip/hip_runtime.h>
#include <math.h>

#define B_ 64
#define E_ 512
#define N_ 2048
#define EPSF 1e-8f

// ws layout (float slots) — round-2 proven layout
#define OFF_ROWMEAN 0              // B*E = 32768
#define OFF_ROWINV  32768          // B*E = 32768
#define OFF_COLPART 65536          // 16*B*N = 2097152
#define OFF_MM      2162688        // 8 u32 (min[3], max[3])
#define OFF_RAW     2162696        // B*3*4096 = 786432
#define OFF_ZPART   2949128        // 16*B*4096 = 4194304

// order-preserving float<->uint map for atomic min/max
__device__ __forceinline__ unsigned mapf(float x) {
    unsigned u = __float_as_uint(x);
    return (u & 0x80000000u) ? ~u : (u | 0x80000000u);
}
__device__ __forceinline__ float unmapf(unsigned m) {
    unsigned u = (m & 0x80000000u) ? (m ^ 0x80000000u) : ~m;
    return __uint_as_float(u);
}

// ---------- kernel 1: fused row stats + column-sum partials (ONE 268MB pass) ----------
// grid (16, B), block 256 = 4 waves; wave w handles rows [ec*32 + w*8, +8).
// KEEP unroll 1 on the row loop + no row caching: VGPR-lean (~80) so the
// HBM-streaming loop keeps ~6 waves/SIMD (round-3's fusion regressed this).
__global__ __launch_bounds__(256) void k_stats(const float* __restrict__ x,
                                               float* __restrict__ rowmean,
                                               float* __restrict__ rowinv,
                                               float* __restrict__ colpart,
                                               unsigned* __restrict__ mm) {
    __shared__ __align__(16) float cs[4][N_];   // 32 KB
    int b = blockIdx.y, ec = blockIdx.x;
    int t = threadIdx.x, w = t >> 6, lane = t & 63;
    if (ec == 0 && b == 0 && t < 6) mm[t] = (t < 3) ? 0xFFFFFFFFu : 0u;

    float colacc[32];
#pragma unroll
    for (int i = 0; i < 32; ++i) colacc[i] = 0.f;
    int ebase = ec * 32 + w * 8;
#pragma unroll 1
    for (int r = 0; r < 8; ++r) {
        int e = ebase + r;
        const float4* row = (const float4*)(x + ((size_t)b * E_ + e) * N_);
        float s = 0.f, sq = 0.f;
#pragma unroll
        for (int i = 0; i < 8; ++i) {
            float4 v = row[lane + 64 * i];
            s += v.x + v.y + v.z + v.w;
            sq = fmaf(v.x, v.x, sq);
            sq = fmaf(v.y, v.y, sq);
            sq = fmaf(v.z, v.z, sq);
            sq = fmaf(v.w, v.w, sq);
            colacc[4 * i + 0] += v.x;
            colacc[4 * i + 1] += v.y;
            colacc[4 * i + 2] += v.z;
            colacc[4 * i + 3] += v.w;
        }
#pragma unroll
        for (int m = 32; m; m >>= 1) {
            s += __shfl_xor(s, m, 64);
            sq += __shfl_xor(sq, m, 64);
        }
        if (lane == 0) {
            float mean = s * (1.0f / N_);
            float var = sq - s * s * (1.0f / N_);
            if (var < 0.f) var = 0.f;
            rowmean[b * E_ + e] = mean;
            rowinv[b * E_ + e] = 1.0f / (sqrtf(var) + EPSF);
        }
    }
    float4* slice = (float4*)cs[w];
#pragma unroll
    for (int i = 0; i < 8; ++i)
        slice[lane + 64 * i] = make_float4(colacc[4 * i], colacc[4 * i + 1],
                                           colacc[4 * i + 2], colacc[4 * i + 3]);
    __syncthreads();
    float* cp = colpart + ((size_t)ec * B_ + b) * N_;
    for (int c = t; c < N_; c += 256)
        cp[c] = cs[0][c] + cs[1][c] + cs[2][c] + cs[3][c];
}

// ---------- kernel 2: Z = Y Y^T partials; one wave per (b, kchunk) ----------
// Staging: per o, ONE full-wave 1KB load (lanes 0-31: row 8o+3 slice,
// lanes 32-63: row 8o+4 slice), halves paired via shfl_xor(32); lanes 0-31
// write swizzled b128 (conflict-free). 64 independent loads -> good MLP.
// LDS image: word(o, 4m+j) = o*128 + 4*(m ^ (o>>3)) + j.
__global__ __launch_bounds__(64) void k_z(const float* __restrict__ x,
                                          const float* __restrict__ rowmean,
                                          const float* __restrict__ rowinv,
                                          float* __restrict__ zpart) {
    __shared__ __align__(16) float Y[64 * 128];   // 32 KB
    int b = blockIdx.x, kc = blockIdx.y, k0 = kc * 128;
    int lane = threadIdx.x;
    const float* xb = x + (size_t)b * E_ * N_;
    const float* rm = rowmean + b * E_;
    const float* ri = rowinv + b * E_;
    int half = lane >> 5;          // 0 -> row 8o+3, 1 -> row 8o+4
    int c = lane & 31;             // float4 chunk within the 128-float K slice

#pragma unroll 8
    for (int o = 0; o < 64; ++o) {
        int r = 8 * o + 3 + half;
        float4 v = *(const float4*)(xb + (size_t)r * N_ + k0 + 4 * c);
        float m = rm[r], s = ri[r];
        float4 p;
        p.x = (v.x - m) * s * 0.5f;
        p.y = (v.y - m) * s * 0.5f;
        p.z = (v.z - m) * s * 0.5f;
        p.w = (v.w - m) * s * 0.5f;
        float4 q;
        q.x = p.x + __shfl_xor(p.x, 32, 64);
        q.y = p.y + __shfl_xor(p.y, 32, 64);
        q.z = p.z + __shfl_xor(p.z, 32, 64);
        q.w = p.w + __shfl_xor(p.w, 32, 64);
        if (half == 0)
            *(float4*)&Y[o * 128 + 4 * (c ^ (o >> 3))] = q;
    }
    __syncthreads();

    int ti = lane >> 3, tj = lane & 7;
    float acc[8][8];
#pragma unroll
    for (int i = 0; i < 8; ++i)
#pragma unroll
        for (int j = 0; j < 8; ++j) acc[i][j] = 0.f;

#pragma unroll 2
    for (int m4 = 0; m4 < 32; ++m4) {
        float4 av[8], bv[8];
#pragma unroll
        for (int a = 0; a < 8; ++a)
            av[a] = *(const float4*)&Y[(8 * ti + a) * 128 + 4 * (m4 ^ ti)];
#pragma unroll
        for (int cc = 0; cc < 8; ++cc)
            bv[cc] = *(const float4*)&Y[(8 * tj + cc) * 128 + 4 * (m4 ^ tj)];
#pragma unroll
        for (int a = 0; a < 8; ++a)
#pragma unroll
            for (int cc = 0; cc < 8; ++cc) {
                acc[a][cc] = fmaf(av[a].x, bv[cc].x, acc[a][cc]);
                acc[a][cc] = fmaf(av[a].y, bv[cc].y, acc[a][cc]);
                acc[a][cc] = fmaf(av[a].z, bv[cc].z, acc[a][cc]);
                acc[a][cc] = fmaf(av[a].w, bv[cc].w, acc[a][cc]);
            }
    }
    float* zp = zpart + ((size_t)kc * B_ + b) * 4096;
#pragma unroll
    for (int a = 0; a < 8; ++a) {
        int rr = (8 * ti + a) * 64 + 8 * tj;
        *(float4*)&zp[rr]     = make_float4(acc[a][0], acc[a][1], acc[a][2], acc[a][3]);
        *(float4*)&zp[rr + 4] = make_float4(acc[a][4], acc[a][5], acc[a][6], acc[a][7]);
    }
}

// ---------- kernel 3: build raw 64x64 views + global min/max ----------
__global__ __launch_bounds__(256) void k_views(const float* __restrict__ rowmean,
                                               const float* __restrict__ colpart,
                                               const float* __restrict__ zpart,
                                               float* __restrict__ raw,
                                               unsigned* __restrict__ mm) {
    int b = blockIdx.x, v = blockIdx.y;
    int t = threadIdx.x;
    __shared__ float g[2116];
    __shared__ int   ti0[64];
    __shared__ int   ti1[64];
    __shared__ float tw[64];
    __shared__ float smin[4], smax[4];

    int gs = (v == 0) ? 23 : 46;
    if (v < 2) {
        int L = (v == 0) ? 512 : 2048;
        int gg = gs * gs;
        for (int i = t; i < gg; i += 256) {
            float val = 0.f;
            if (i < L) {
                if (v == 0) {
                    val = rowmean[b * E_ + i];
                } else {
#pragma unroll
                    for (int ch = 0; ch < 16; ++ch)
                        val += colpart[((size_t)ch * B_ + b) * N_ + i];
                    val *= (1.0f / 512.0f);
                }
            }
            g[i] = val;
        }
        if (t < 64) {
            double scd = (double)gs / 64.0;
            double sp = ((double)t + 0.5) * scd - 0.5;
            if (sp < 0.0) sp = 0.0;
            double up = (double)(gs - 1);
            if (sp > up) sp = up;
            int i0 = (int)sp;
            ti0[t] = i0;
            ti1[t] = (i0 + 1 < gs) ? i0 + 1 : gs - 1;
            tw[t] = (float)(sp - (double)i0);
        }
    }
    __syncthreads();

    float lmin = INFINITY, lmax = -INFINITY;
    for (int it = 0; it < 16; ++it) {
        int pix = t + 256 * it;
        float val;
        if (v == 2) {
            val = 0.f;
#pragma unroll
            for (int s = 0; s < 16; ++s)
                val += zpart[((size_t)s * B_ + b) * 4096 + pix];
        } else {
            int o = pix >> 6, p = pix & 63;
            int i0 = ti0[o], i1 = ti1[o];
            float wh = tw[o];
            int j0 = ti0[p], j1 = ti1[p];
            float ww = tw[p];
            float top = g[i0 * gs + j0] * (1.f - ww) + g[i0 * gs + j1] * ww;
            float bot = g[i1 * gs + j0] * (1.f - ww) + g[i1 * gs + j1] * ww;
            val = top * (1.f - wh) + bot * wh;
        }
        raw[((size_t)b * 3 + v) * 4096 + pix] = val;
        lmin = fminf(lmin, val);
        lmax = fmaxf(lmax, val);
    }

    int lane = t & 63, wid = t >> 6;
#pragma unroll
    for (int m = 32; m; m >>= 1) {
        lmin = fminf(lmin, __shfl_xor(lmin, m, 64));
        lmax = fmaxf(lmax, __shfl_xor(lmax, m, 64));
    }
    if (lane == 0) { smin[wid] = lmin; smax[wid] = lmax; }
    __syncthreads();
    if (t == 0) {
        float mn = fminf(fminf(smin[0], smin[1]), fminf(smin[2], smin[3]));
        float mx = fmaxf(fmaxf(smax[0], smax[1]), fmaxf(smax[2], smax[3]));
        atomicMin(&mm[v], mapf(mn));
        atomicMax(&mm[3 + v], mapf(mx));
    }
}

// ---------- kernel 4: global minmax-normalize -> out ----------
__global__ __launch_bounds__(256) void k_norm(const float* __restrict__ raw,
                                              const unsigned* __restrict__ mm,
                                              float* __restrict__ out) {
    int b = blockIdx.x, v = blockIdx.y;
    int t = threadIdx.x;
    float lo = unmapf(mm[v]);
    float hi = unmapf(mm[3 + v]);
    float d = hi - lo;
    bool zero = (d < EPSF);
    float inv = 1.0f / (d + EPSF);
    size_t base = ((size_t)b * 3 + v) * 4096;
    for (int it = 0; it < 16; ++it) {
        int pix = t + 256 * it;
        float r = raw[base + pix];
        out[base + pix] = zero ? 0.f : (r - lo) * inv;
    }
}

extern "C" void kernel_launch(void* const* d_in, const int* in_sizes, int n_in,
                              void* d_out, int out_size, void* d_ws, size_t ws_size,
                              hipStream_t stream) {
    const float* x = (const float*)d_in[0];
    float* ws = (float*)d_ws;
    float* rowmean = ws + OFF_ROWMEAN;
    float* rowinv  = ws + OFF_ROWINV;
    float* colpart = ws + OFF_COLPART;
    unsigned* mm   = (unsigned*)(ws + OFF_MM);
    float* raw     = ws + OFF_RAW;
    float* zpart   = ws + OFF_ZPART;
    float* out     = (float*)d_out;

    k_stats<<<dim3(16, B_), 256, 0, stream>>>(x, rowmean, rowinv, colpart, mm);
    k_z<<<dim3(B_, 16), 64, 0, stream>>>(x, rowmean, rowinv, zpart);
    k_views<<<dim3(B_, 3), 256, 0, stream>>>(rowmean, colpart, zpart, raw, mm);
    k_norm<<<dim3(B_, 3), 256, 0, stream>>>(raw, mm, out);
}